// Round 12
// baseline (454.228 us; speedup 1.0000x reference)
//
#include <hip/hip_runtime.h>

typedef unsigned short u16;
typedef unsigned int u32;
typedef unsigned long long u64;

typedef __attribute__((ext_vector_type(8))) short short8;   // 8 bf16 = 4 VGPRs
typedef __attribute__((ext_vector_type(4))) float floatx4;  // MFMA accumulator

__device__ __forceinline__ float b2f(u16 h) {
  u32 u = ((u32)h) << 16;
  return __builtin_bit_cast(float, u);
}
__device__ __forceinline__ u16 f2b(float f) {
  u32 u = __builtin_bit_cast(u32, f);
  u32 r = 0x7FFFu + ((u >> 16) & 1u);  // RNE
  return (u16)((u + r) >> 16);
}

// async global->LDS, 16B per lane. LDS dest = wave-uniform base + lane*16.
__device__ __forceinline__ void gl_lds16(const void* g, void* l) {
  __builtin_amdgcn_global_load_lds(
      (__attribute__((address_space(1))) void*)(u64)g,
      (__attribute__((address_space(3))) void*)(u32)(u64)l, 16, 0, 0);
}

// raw workgroup barrier WITHOUT the compiler's vmcnt(0) drain, so
// global_load_lds prefetches stay in flight across it.
__device__ __forceinline__ void wg_barrier() {
  asm volatile("" ::: "memory");
  __builtin_amdgcn_s_barrier();
  asm volatile("" ::: "memory");
}

// trunc-pack 8 fp32 -> 8 bf16 (verified byte order, round-0 kernel)
__device__ __forceinline__ short8 cvt2(const float4& a, const float4& b) {
  union { u32 w[4]; short8 s; } cv;
  const u32* x = (const u32*)&a;
  const u32* y = (const u32*)&b;
  cv.w[0] = __builtin_amdgcn_perm(x[1], x[0], 0x07060302u);
  cv.w[1] = __builtin_amdgcn_perm(x[3], x[2], 0x07060302u);
  cv.w[2] = __builtin_amdgcn_perm(y[1], y[0], 0x07060302u);
  cv.w[3] = __builtin_amdgcn_perm(y[3], y[2], 0x07060302u);
  return cv.s;
}

enum { EPI_PHI_BIAS = 0, EPI_BIAS = 1, EPI_NONE = 2, EPI_ZSCALE = 3,
       EPI_BIAS_F32 = 4, EPI_ZBIAS_F32 = 5 };

// C[m,n] = sum_k A[m,k] * B[n,k]  (K-contiguous). 256x256x64 tile, 8 waves
// (2M x 4N, 128x64 per wave), double-buffered 128KiB LDS, counted-vmcnt
// pipeline (R8 verified skeleton; per-dispatch rocprof timings swing ±30%
// across runs — judge by totals).
//
// A_F32 (round-12): SINGLE full-tile reg bank (32 VGPR; two banks spilled in
// R9: 64+128acc+108 > 256). LINEAR phys-slot ownership (conflict-free
// ds_write_b128: one LDS row = 128B = full bank wrap, so only lane-linear
// writes are clean). Thread t owns slots {t,t+512,t+1024,t+1536}; global src
// row j>>3, chunk (j&7)^(row&7). Schedule per iter (issue order: A x8 then
// B x4 at TOP, 12 in flight; buffer cur already published by prev barrier):
//   mid (after ks0, 32 MFMAs of cover): vmcnt(4) -> the 8 A loads (oldest)
//        landed; cvt+ds_write the full tile into nxt.
//   end (after ks1): vmcnt(0) -> B landed (issued at TOP: cover = whole
//        compute phase, vs R8's mid-issued Ar23 with ~16-MFMA cover — the
//        ~600cy exposed stall this round removes); lgkmcnt(0) -> writes
//        committed; barrier -> tile it+1 visible to all waves.
//   Per-wave counters + barrier => cross-wave validity (round-3 lesson).
// WAR: iter it+1's staging targets buf[(it+2)&1] = cur(it), last read in
// iter it; the end-of-it barrier separates (reads consumed into MFMAs).
// LDS layout per buffer: A[256 rows][8 slots of 16B], phys slot = c ^ (row&7)
// (conflict-free ds_read_b128); B at +32768, same scheme. bf16 staging uses
// linear LDS dest + pre-swizzled global src (gl_lds), counted vmcnt(8).
// Block swizzle: XCD-chunked remap, N-tiles of one M-slab adjacent.
// gridDim.y==4, (gx*gy)%8==0 for all launches.
// Split-K: blockIdx.z = kslice*(abmask+1)+batch.
// DUAL: bz selects operand set 1 (A2/B2/bias2/C2, no phi) vs set 0 (phi).
// KSUM (DUAL && TRANS_OUT && phi_on): epilogue column sums of the phi'd tile
// atomicAdd into ksum_out[batch*1024+col] (fused Ksum).
template<int EPI, bool A_F32, bool TRANS_OUT, bool DUAL>
__global__ __launch_bounds__(512, 2)
void gemm_bt(const void* __restrict__ Aall, const u16* __restrict__ Ball,
             const float* __restrict__ bias, const float* __restrict__ Zall,
             void* __restrict__ Call,
             int M, int N, int K, int ldA, int ldB, int ldC,
             long sAb, long sBb, long sCb, long sZb, int abmask, int kshift,
             const void* __restrict__ Aall2, const u16* __restrict__ Ball2,
             const float* __restrict__ bias2, void* __restrict__ Call2,
             float* __restrict__ ksum_out)
{
  constexpr int BOFF   = 32768;        // B tile offset within one buffer
  constexpr int STRIDE = 65536;        // one stage buffer (A 32K + B 32K)
  extern __shared__ char smem[];       // 131072 B dynamic

  const int tid  = threadIdx.x;
  const int lane = tid & 63;
  const int wave = tid >> 6;
  const int wm = wave >> 2, wn = wave & 3;   // 2x4 waves, 128x64 each
  const int fl = lane & 15;
  const int q  = lane >> 4;
  const int r4 = q * 4;

  // XCD-chunked block swizzle; consecutive remapped ids iterate the 4 N-tiles
  // of one M-tile.
  const int orig = blockIdx.x + gridDim.x * blockIdx.y;
  const int nwg8 = (gridDim.x * gridDim.y) >> 3;
  const int wsw  = (orig & 7) * nwg8 + (orig >> 3);
  const int bm0 = (wsw >> 2) * 256;          // gridDim.y == 4 in all launches
  const int bn0 = (wsw & 3) * 256;

  const int bz = blockIdx.z;
  const int abz = bz & abmask;
  const int kbase = (bz >> kshift) * K;

  const void* Asel = Aall; const u16* Bsel = Ball;
  const float* biasSel = bias; void* Csel = Call;
  bool phi_on = true;
  if constexpr (DUAL) {
    if (bz) { Asel = Aall2; Bsel = Ball2; biasSel = bias2; Csel = Call2; phi_on = false; }
  }

  const u16* Bp = Bsel + (size_t)abz * sBb + kbase;

  // ---- B staging addresses (global per-lane pre-swizzled; LDS dest linear) --
  const u16* gB[4]; int sLo[4];
  #pragma unroll
  for (int n = 0; n < 4; ++n) {
    int j = n * 512 + tid;
    int row = j >> 3, pc = j & 7, c = pc ^ (row & 7);
    gB[n] = Bp + (size_t)(bn0 + row) * ldB + c * 8;
    sLo[n] = (n * 512 + wave * 64) * 16;
  }

  // ---- fragment LDS byte offsets (within one stage buffer, ks=0) ----
  int aoff[8], boff[4];
  #pragma unroll
  for (int i = 0; i < 8; ++i) {
    int row = wm * 128 + i * 16 + fl;
    aoff[i] = (row * 8 + (q ^ (row & 7))) * 16;
  }
  #pragma unroll
  for (int i = 0; i < 4; ++i) {
    int row = wn * 64 + i * 16 + fl;
    boff[i] = BOFF + (row * 8 + (q ^ (row & 7))) * 16;
  }

  floatx4 zero = {0.f, 0.f, 0.f, 0.f};
  floatx4 acc[8][4];
  #pragma unroll
  for (int i = 0; i < 8; ++i)
    #pragma unroll
    for (int j = 0; j < 4; ++j) acc[i][j] = zero;

  auto stageB = [&](int k0, char* base) {
    #pragma unroll
    for (int n = 0; n < 4; ++n) gl_lds16(gB[n] + k0, base + BOFF + sLo[n]);
  };

  const int NIT = K >> 6;                 // K-tiles of 64

  if constexpr (A_F32) {
    const float* Af = (const float*)Asel + (size_t)abz * sAb + kbase;
    // linear phys-slot ownership: slot j = n*512 + tid
    const float* gAs[4]; int wOff[4];
    #pragma unroll
    for (int n = 0; n < 4; ++n) {
      int j = n * 512 + tid;
      int row = j >> 3, c = (j & 7) ^ (row & 7);
      gAs[n] = Af + (size_t)(bm0 + row) * ldA + c * 8;
      wOff[n] = j * 16;
    }

    float4 Ar[8];                         // full A-tile in regs (32 VGPR)
    auto aloadFull = [&](int k0) {
      #pragma unroll
      for (int n = 0; n < 4; ++n) {
        Ar[2 * n]     = *(const float4*)(gAs[n] + k0);
        Ar[2 * n + 1] = *(const float4*)(gAs[n] + k0 + 4);
      }
    };
    auto awriteFull = [&](char* base) {
      #pragma unroll
      for (int n = 0; n < 4; ++n)
        *(short8*)(base + wOff[n]) = cvt2(Ar[2 * n], Ar[2 * n + 1]);
    };

    short8 aF[4], bF[4];
    auto rdB = [&](const char* base, int ks) {
      #pragma unroll
      for (int i = 0; i < 4; ++i) bF[i] = *(const short8*)(base + (boff[i] ^ (ks * 64)));
    };
    auto rdA = [&](const char* base, int mh, int ks) {
      #pragma unroll
      for (int i = 0; i < 4; ++i) aF[i] = *(const short8*)(base + (aoff[mh * 4 + i] ^ (ks * 64)));
    };
    auto mma = [&](int mh) {
      __builtin_amdgcn_s_setprio(1);
      #pragma unroll
      for (int i = 0; i < 4; ++i)
        #pragma unroll
        for (int ni = 0; ni < 4; ++ni)
          acc[mh * 4 + i][ni] =
              __builtin_amdgcn_mfma_f32_16x16x32_bf16(aF[i], bF[ni], acc[mh * 4 + i][ni], 0, 0, 0);
      __builtin_amdgcn_s_setprio(0);
    };

    // prologue: stage + publish tile 0
    aloadFull(0); stageB(0, smem);
    asm volatile("s_waitcnt vmcnt(4)" ::: "memory");   // A regs landed
    awriteFull(smem);
    asm volatile("s_waitcnt vmcnt(0)" ::: "memory");   // B landed
    asm volatile("s_waitcnt lgkmcnt(0)" ::: "memory"); // A writes committed
    wg_barrier();                                      // buf0 published

    for (int it = 0; it < NIT; ++it) {
      const char* cur = smem + (it & 1) * STRIDE;
      char* nxt = smem + ((it + 1) & 1) * STRIDE;
      const bool pre = (it + 1 < NIT);
      if (pre) {
        aloadFull((it + 1) * 64);        // 8 issues (oldest)
        stageB((it + 1) * 64, nxt);      // +4 = 12 in flight
      }
      // ---- ks = 0 ----
      rdB(cur, 0);
      rdA(cur, 0, 0); mma(0);
      rdA(cur, 1, 0); mma(1);
      if (pre) {
        asm volatile("s_waitcnt vmcnt(4)" ::: "memory");   // A(it+1) regs landed
        awriteFull(nxt);
      }
      // ---- ks = 1 ----
      rdB(cur, 1);
      rdA(cur, 0, 1); mma(0);
      rdA(cur, 1, 1); mma(1);
      if (pre) {
        asm volatile("s_waitcnt vmcnt(0)" ::: "memory");   // B(it+1) landed (top-issued)
        asm volatile("s_waitcnt lgkmcnt(0)" ::: "memory"); // A writes committed
      }
      wg_barrier();                        // publish tile it+1; WAR for cur
    }
  } else {
    // round-4 verified bf16 path: A via gl_lds, counted vmcnt(8)
    const u16* Ah = (const u16*)Asel + (size_t)abz * sAb + kbase;
    const u16* gA[4];
    #pragma unroll
    for (int n = 0; n < 4; ++n) {
      int j = n * 512 + tid;
      int row = j >> 3, pc = j & 7, c = pc ^ (row & 7);
      gA[n] = Ah + (size_t)(bm0 + row) * ldA + c * 8;
    }
    auto stage = [&](int k0, char* base) {
      #pragma unroll
      for (int n = 0; n < 4; ++n) gl_lds16(gA[n] + k0, base + sLo[n]);
      stageB(k0, base);
    };
    auto compute = [&](const char* base) {
      #pragma unroll
      for (int ks = 0; ks < 2; ++ks) {
        short8 aF[8], bF[4];
        #pragma unroll
        for (int i = 0; i < 8; ++i) aF[i] = *(const short8*)(base + (aoff[i] ^ (ks * 64)));
        #pragma unroll
        for (int i = 0; i < 4; ++i) bF[i] = *(const short8*)(base + (boff[i] ^ (ks * 64)));
        __builtin_amdgcn_s_setprio(1);
        #pragma unroll
        for (int mi = 0; mi < 8; ++mi)
          #pragma unroll
          for (int ni = 0; ni < 4; ++ni)
            acc[mi][ni] = __builtin_amdgcn_mfma_f32_16x16x32_bf16(aF[mi], bF[ni], acc[mi][ni], 0, 0, 0);
        __builtin_amdgcn_s_setprio(0);
      }
    };
    stage(0, smem);
    for (int it = 0; it < NIT; ++it) {
      if (it + 1 < NIT) {
        stage((it + 1) * 64, smem + ((it + 1) & 1) * STRIDE);
        asm volatile("s_waitcnt vmcnt(8)" ::: "memory");
      } else {
        asm volatile("s_waitcnt vmcnt(0)" ::: "memory");
      }
      wg_barrier();
      compute(smem + (it & 1) * STRIDE);
      if (it + 1 < NIT) wg_barrier();
    }
  }

  if constexpr (!TRANS_OUT) {
    #pragma unroll
    for (int mi = 0; mi < 8; ++mi) {
      #pragma unroll
      for (int ni = 0; ni < 4; ++ni) {
        int col = bn0 + wn * 64 + ni * 16 + fl;
        #pragma unroll
        for (int r = 0; r < 4; ++r) {
          int row = bm0 + wm * 128 + mi * 16 + r4 + r;
          float vv = acc[mi][ni][r];
          if constexpr (EPI == EPI_PHI_BIAS) {
            vv += biasSel[col];
            if (phi_on) vv = __expf(-0.5f * vv * vv);
          }
          if constexpr (EPI == EPI_BIAS || EPI == EPI_BIAS_F32) vv += biasSel[col];
          if constexpr (EPI == EPI_ZSCALE) vv *= Zall[(size_t)abz * sZb + row];
          if constexpr (EPI == EPI_ZBIAS_F32)
            vv = vv * Zall[(size_t)abz * sZb + row] + biasSel[col];
          if constexpr (EPI == EPI_BIAS_F32 || EPI == EPI_ZBIAS_F32)
            ((float*)Csel)[(size_t)bz * sCb + (size_t)row * ldC + col] = vv;
          else
            ((u16*)Csel)[(size_t)bz * sCb + (size_t)row * ldC + col] = f2b(vv);
        }
      }
    }
  } else {
    // transpose through LDS in two 128-t-row passes, then coalesced 16B
    // stores into [4][N][4096]. sT = [256 d][136 t-pad] u16 = 69632 B.
    float ks[4] = {0.f, 0.f, 0.f, 0.f};   // fused Ksum column partials
    __syncthreads();                      // all compute reads done, smem free
    u16* sT = (u16*)smem;
    #pragma unroll
    for (int h = 0; h < 2; ++h) {
      if (wm == h) {
        #pragma unroll
        for (int mi = 0; mi < 8; ++mi) {
          #pragma unroll
          for (int ni = 0; ni < 4; ++ni) {
            int colL = wn * 64 + ni * 16 + fl;
            int row0 = mi * 16 + r4;
            float bcol = biasSel[bn0 + colL];
            ushort4 hh;
            #pragma unroll
            for (int r = 0; r < 4; ++r) {
              float vv = acc[mi][ni][r] + bcol;
              if (phi_on) vv = __expf(-0.5f * vv * vv);
              if constexpr (DUAL) ks[ni] += vv;
              ((u16*)&hh)[r] = f2b(vv);
            }
            *(ushort4*)(sT + colL * 136 + row0) = hh;
          }
        }
      }
      __syncthreads();
      #pragma unroll
      for (int i = 0; i < 8; ++i) {
        int c = i * 512 + tid;            // 4096 x 16B chunks (256 d x 128 t)
        int dloc = c >> 4, t16 = (c & 15) * 8;
        int4 vv = *(const int4*)(sT + dloc * 136 + t16);
        int gd = bn0 + dloc;
        int gt = bm0 + h * 128 + t16;
        int batch = gt >> 12, tt = gt & 4095;
        *(int4*)((u16*)Csel + ((size_t)batch * N + gd) * 4096 + tt) = vv;
      }
      __syncthreads();
    }
    if constexpr (DUAL) {
      if (phi_on) {                       // K-projection blocks: fused Ksum
        #pragma unroll
        for (int ni = 0; ni < 4; ++ni) {
          float s = ks[ni];
          s += __shfl_xor(s, 16, 64);
          s += __shfl_xor(s, 32, 64);
          if (q == 0)
            atomicAdd(ksum_out + ((bm0 >> 12) << 10) + bn0 + wn * 64 + ni * 16 + fl, s);
        }
      }
    }
  }
}

__global__ __launch_bounds__(256)
void wconv(const float* __restrict__ w0, const float* __restrict__ w1,
           const float* __restrict__ w2, const float* __restrict__ w3,
           u16* __restrict__ dst, float* __restrict__ ksum) {
  if (blockIdx.x == 0) {                 // zero Ksum [4][1024] for fused atomics
    float4 z = {0.f, 0.f, 0.f, 0.f};
    #pragma unroll
    for (int i = 0; i < 4; ++i)
      *(float4*)(ksum + threadIdx.x * 16 + i * 4) = z;
  }
  unsigned e = blockIdx.x * 256 + threadIdx.x;
  int mat = e >> 18;
  size_t off = (size_t)(e & 262143) * 4;
  const float* src = mat == 0 ? w0 : mat == 1 ? w1 : mat == 2 ? w2 : w3;
  float4 v = *(const float4*)(src + off);
  ushort4 h;
  h.x = f2b(v.x); h.y = f2b(v.y); h.z = f2b(v.z); h.w = f2b(v.w);
  *(ushort4*)(dst + (size_t)mat * 1048576 + off) = h;
}

// out[i] = round(sum over 4 K-slices of bf16 partials), 4M elems, slice stride 4M
__global__ __launch_bounds__(256)
void reduce4(const u16* __restrict__ P, u16* __restrict__ out) {
  size_t i = ((size_t)blockIdx.x * 256 + threadIdx.x) * 8;
  int4 a = *(const int4*)(P + i);
  int4 b = *(const int4*)(P + i + 4194304);
  int4 c = *(const int4*)(P + i + 8388608);
  int4 d = *(const int4*)(P + i + 12582912);
  const u16* ha = (const u16*)&a; const u16* hb = (const u16*)&b;
  const u16* hc = (const u16*)&c; const u16* hd = (const u16*)&d;
  ushort4 o0, o1;
  #pragma unroll
  for (int j = 0; j < 8; ++j) {
    float s = b2f(ha[j]) + b2f(hb[j]) + b2f(hc[j]) + b2f(hd[j]);
    ((u16*)(j < 4 ? &o0 : &o1))[j & 3] = f2b(s);
  }
  *(ushort4*)(out + i) = o0;
  *(ushort4*)(out + i + 4) = o1;
}

// Z[t] = 1/(Q[t,:]·Ksum[batch,:] + 1e-6); one wave per token
__global__ __launch_bounds__(256)
void zden(const u16* __restrict__ Qb, const float* __restrict__ Ksum,
          float* __restrict__ Z) {
  int lane = threadIdx.x & 63;
  int t = blockIdx.x * 4 + (threadIdx.x >> 6);
  const u16* qp = Qb + (size_t)t * 1024;
  const float* ks = Ksum + (size_t)(t >> 12) * 1024;
  float s = 0.f;
  #pragma unroll
  for (int i = 0; i < 2; ++i) {
    int idx = i * 512 + lane * 8;
    int4 d = *(const int4*)(qp + idx);
    const u16* h = (const u16*)&d;
    float4 k0 = *(const float4*)(ks + idx);
    float4 k1 = *(const float4*)(ks + idx + 4);
    s += b2f(h[0]) * k0.x + b2f(h[1]) * k0.y + b2f(h[2]) * k0.z + b2f(h[3]) * k0.w
       + b2f(h[4]) * k1.x + b2f(h[5]) * k1.y + b2f(h[6]) * k1.z + b2f(h[7]) * k1.w;
  }
  #pragma unroll
  for (int off = 32; off; off >>= 1) s += __shfl_xor(s, off, 64);
  if (lane == 0) Z[t] = 1.0f / (s + 1e-6f);
}

extern "C" void kernel_launch(void* const* d_in, const int* in_sizes, int n_in,
                              void* d_out, int out_size, void* d_ws, size_t ws_size,
                              hipStream_t stream) {
  const float* q  = (const float*)d_in[0];
  const float* k  = (const float*)d_in[1];
  const float* v  = (const float*)d_in[2];
  const float* Wq = (const float*)d_in[3];
  const float* bq = (const float*)d_in[4];
  const float* Wk = (const float*)d_in[5];
  const float* bk = (const float*)d_in[6];
  const float* Wv = (const float*)d_in[7];
  const float* bv = (const float*)d_in[8];
  const float* Wo = (const float*)d_in[9];
  const float* bo = (const float*)d_in[10];
  float* out = (float*)d_out;

  // workspace layout (~112.1 MiB) with aliasing:
  u16* Wqb = (u16*)d_ws;                 // 4x 1024x1024 bf16 = 8 MiB
  u16* Wkb = Wqb + 1048576;
  u16* Wvb = Wkb + 1048576;
  u16* Wob = Wvb + 1048576;
  u16* Qb  = Wob + 1048576;              // [16384][1024] bf16, 32 MiB
  u16* KT  = Qb  + 16777216;             // [4][1024][4096] bf16, 32 MiB
  u16* VT  = KT  + 16777216;             // [4][1024][4096] bf16, 32 MiB
  u16* KVr = VT  + 16777216;             // [4][1024(d)][1024(l)] bf16, 8 MiB
  float* Ksum = (float*)(KVr + 4194304); // [4][1024] f32 (atomically built)
  float* Z    = Ksum + 4096;             // [16384] f32
  u16* Pkv = Qb;   // S2 split-K partials, before Q-proj overwrites
  u16* Pg  = VT;   // G split-K partials, after VT dead
  u16* Gp  = KT;   // G' [4][1024(n)][1024(d)], after KT dead

  constexpr size_t LDS = 131072;

  wconv<<<4096, 256, 0, stream>>>(Wq, Wk, Wv, Wo, Wqb, Ksum);

  // K,V projections in ONE dispatch (grid z: 0=K with phi + fused Ksum,
  // 1=V bias-only). A = fp32 k / v directly (in-kernel conversion).
  dim3 gkv(64, 4, 2);
  gemm_bt<EPI_PHI_BIAS, true, true, true><<<gkv, 512, LDS, stream>>>(
      k, Wkb, bk, nullptr, KT, 16384, 1024, 1024, 1024, 1024, 0,
      0, 0, 0, 0, 0, 30, v, Wvb, bv, VT, Ksum);

  // S2: KVr[d,l] = sum_t KT[d,t]*VT[l,t], split-K x4 (z = kslice*4+batch)
  dim3 g2(4, 4, 16);
  gemm_bt<EPI_NONE, false, false, false><<<g2, 512, LDS, stream>>>(
      KT, VT, nullptr, nullptr, Pkv, 1024, 1024, 1024, 4096, 4096, 1024,
      4194304L, 4194304L, 1048576L, 0, 3, 2, nullptr, nullptr, nullptr, nullptr, nullptr);
  reduce4<<<2048, 256, 0, stream>>>(Pkv, KVr);

  // Q projection from fp32 q (overwrites partials region — stream-ordered)
  dim3 g1(64, 4, 1);
  gemm_bt<EPI_PHI_BIAS, true, false, false><<<g1, 512, LDS, stream>>>(
      q, Wqb, bq, nullptr, Qb, 16384, 1024, 1024, 1024, 1024, 1024,
      0, 0, 0, 0, 0, 30, nullptr, nullptr, nullptr, nullptr, nullptr);

  zden<<<4096, 256, 0, stream>>>(Qb, Ksum, Z);

  // G'[n,d] = sum_l Wob[n,l]*KVr[d,l], split-K x4 (K=256/slice); Wo folded in.
  dim3 gg(4, 4, 16);
  gemm_bt<EPI_NONE, false, false, false><<<gg, 512, LDS, stream>>>(
      Wob, KVr, nullptr, nullptr, Pg, 1024, 1024, 256, 1024, 1024, 1024,
      0L, 1048576L, 1048576L, 0, 3, 2, nullptr, nullptr, nullptr, nullptr, nullptr);
  reduce4<<<2048, 256, 0, stream>>>(Pg, Gp);

  // final: out[t,n] = Z[t]*(sum_d Qb[t,d]*G'[n,d]) + bo[n], fp32 out
  dim3 gf(16, 4, 4);
  gemm_bt<EPI_ZBIAS_F32, false, false, false><<<gf, 512, LDS, stream>>>(
      Qb, Gp, bo, Z, out, 4096, 1024, 1024, 1024, 1024, 1024,
      4194304L, 1048576L, 4194304L, 4096L, 3, 30, nullptr, nullptr, nullptr, nullptr, nullptr);
}

// Round 13
// 415.443 us; speedup vs baseline: 1.0934x; 1.0934x over previous
//
#include <hip/hip_runtime.h>

typedef unsigned short u16;
typedef unsigned int u32;
typedef unsigned long long u64;

typedef __attribute__((ext_vector_type(8))) short short8;   // 8 bf16 = 4 VGPRs
typedef __attribute__((ext_vector_type(4))) float floatx4;  // MFMA accumulator

__device__ __forceinline__ float b2f(u16 h) {
  u32 u = ((u32)h) << 16;
  return __builtin_bit_cast(float, u);
}
__device__ __forceinline__ u16 f2b(float f) {
  u32 u = __builtin_bit_cast(u32, f);
  u32 r = 0x7FFFu + ((u >> 16) & 1u);  // RNE
  return (u16)((u + r) >> 16);
}

// async global->LDS, 16B per lane. LDS dest = wave-uniform base + lane*16.
__device__ __forceinline__ void gl_lds16(const void* g, void* l) {
  __builtin_amdgcn_global_load_lds(
      (__attribute__((address_space(1))) void*)(u64)g,
      (__attribute__((address_space(3))) void*)(u32)(u64)l, 16, 0, 0);
}

// raw workgroup barrier WITHOUT the compiler's vmcnt(0) drain, so
// global_load_lds prefetches stay in flight across it.
__device__ __forceinline__ void wg_barrier() {
  asm volatile("" ::: "memory");
  __builtin_amdgcn_s_barrier();
  asm volatile("" ::: "memory");
}

// trunc-pack 8 fp32 -> 8 bf16 (verified byte order, round-0 kernel)
__device__ __forceinline__ short8 cvt2(const float4& a, const float4& b) {
  union { u32 w[4]; short8 s; } cv;
  const u32* x = (const u32*)&a;
  const u32* y = (const u32*)&b;
  cv.w[0] = __builtin_amdgcn_perm(x[1], x[0], 0x07060302u);
  cv.w[1] = __builtin_amdgcn_perm(x[3], x[2], 0x07060302u);
  cv.w[2] = __builtin_amdgcn_perm(y[1], y[0], 0x07060302u);
  cv.w[3] = __builtin_amdgcn_perm(y[3], y[2], 0x07060302u);
  return cv.s;
}

enum { EPI_PHI_BIAS = 0, EPI_BIAS = 1, EPI_NONE = 2, EPI_ZSCALE = 3,
       EPI_BIAS_F32 = 4, EPI_ZBIAS_F32 = 5 };

// C[m,n] = sum_k A[m,k] * B[n,k]  (K-contiguous). 256x256x64 tile, 8 waves
// (2M x 4N, 128x64 per wave). Per-dispatch rocprof timings swing ±30% across
// runs — judge by totals.
//
// A_F32 (round-13): DEEP-IN-TIME pipeline at R8's register cost.
//   LDS (160K total): A double-buffer 2x32K @ 0; B TRIPLE-buffer 3x32K @ 64K.
//   Single 32-VGPR A bank; loads issued at mid(it) for tile it+2 (bank freed
//   by the awrite just before), so every load is in flight >= 1 full iter
//   (~1100cy > ~900cy HBM) before its wait. B staged 2 tiles ahead.
//   Steady iter it (issue order: B(it+2) @top, A(it+2) @mid):
//     top: stageB(it+2 -> BBUF[(it+2)%3])
//     ks0 compute (32 MFMA)
//     mid: vmcnt(4)  -> all but B(it+2)'s 4 landed => A(it+1) AND B(it+1)
//          confirmed (cover 1 / 1.5 iters); awrite A(it+1); aload A(it+2)
//     ks1 compute
//     end: lgkmcnt(0) (A-writes committed); barrier. NO vmem drain in loop.
//   Tail: it+2==NIT -> mid vmcnt(0) (drains last A+B, cover ~2 iters);
//   last iter skips staging. Prologue: aload A0; stageB 0,1; vmcnt(8) [A0
//   landed, younger=B0+B1]; awrite A0; aload A1; vmcnt(12) [B0 landed,
//   younger=B1+A1]; lgkmcnt(0); barrier.  (NIT>=2 for all our shapes.)
//   asm "memory" waits pin vmem issue order; per-wave counters + barrier =>
//   cross-wave validity (round-3 lesson). WAR: each LDS buffer has exactly
//   one barrier between last read and rewrite (B: read it-1, staged top of
//   it; A: read it-1, written mid of it) — same discipline as R4/R8.
//   Lane-linear phys-slot ownership for A writes (slot j = n*512+tid;
//   one LDS row = 128B = full bank wrap => only lane-linear is clean).
// bf16 path: R4-verified gl_lds A+B, counted vmcnt(8), 2x64K buffers.
// LDS layout per buffer: [256 rows][8 slots of 16B], phys slot = c^(row&7)
// (conflict-free ds_read_b128). Block swizzle: XCD-chunked remap, N-tiles of
// one M-slab adjacent. gridDim.y==4, (gx*gy)%8==0 for all launches.
// Split-K: blockIdx.z = kslice*(abmask+1)+batch.
// DUAL: bz selects operand set 1 (A2/B2/bias2/C2, no phi) vs set 0 (phi).
// KSUM (DUAL && TRANS_OUT && phi_on): epilogue column sums of the phi'd tile
// atomicAdd into ksum_out[batch*1024+col] (fused Ksum).
template<int EPI, bool A_F32, bool TRANS_OUT, bool DUAL>
__global__ __launch_bounds__(512, 2)
void gemm_bt(const void* __restrict__ Aall, const u16* __restrict__ Ball,
             const float* __restrict__ bias, const float* __restrict__ Zall,
             void* __restrict__ Call,
             int M, int N, int K, int ldA, int ldB, int ldC,
             long sAb, long sBb, long sCb, long sZb, int abmask, int kshift,
             const void* __restrict__ Aall2, const u16* __restrict__ Ball2,
             const float* __restrict__ bias2, void* __restrict__ Call2,
             float* __restrict__ ksum_out)
{
  constexpr int BOFF   = 32768;        // bf16 path: B offset within buffer
  constexpr int STRIDE = 65536;        // bf16 path: one stage buffer (A+B)
  extern __shared__ char smem[];

  const int tid  = threadIdx.x;
  const int lane = tid & 63;
  const int wave = tid >> 6;
  const int wm = wave >> 2, wn = wave & 3;   // 2x4 waves, 128x64 each
  const int fl = lane & 15;
  const int q  = lane >> 4;
  const int r4 = q * 4;

  // XCD-chunked block swizzle; consecutive remapped ids iterate the 4 N-tiles
  // of one M-tile.
  const int orig = blockIdx.x + gridDim.x * blockIdx.y;
  const int nwg8 = (gridDim.x * gridDim.y) >> 3;
  const int wsw  = (orig & 7) * nwg8 + (orig >> 3);
  const int bm0 = (wsw >> 2) * 256;          // gridDim.y == 4 in all launches
  const int bn0 = (wsw & 3) * 256;

  const int bz = blockIdx.z;
  const int abz = bz & abmask;
  const int kbase = (bz >> kshift) * K;

  const void* Asel = Aall; const u16* Bsel = Ball;
  const float* biasSel = bias; void* Csel = Call;
  bool phi_on = true;
  if constexpr (DUAL) {
    if (bz) { Asel = Aall2; Bsel = Ball2; biasSel = bias2; Csel = Call2; phi_on = false; }
  }

  const u16* Bp = Bsel + (size_t)abz * sBb + kbase;

  // ---- B staging addresses (global per-lane pre-swizzled; LDS dest linear) --
  const u16* gB[4]; int sLo[4];
  #pragma unroll
  for (int n = 0; n < 4; ++n) {
    int j = n * 512 + tid;
    int row = j >> 3, pc = j & 7, c = pc ^ (row & 7);
    gB[n] = Bp + (size_t)(bn0 + row) * ldB + c * 8;
    sLo[n] = (n * 512 + wave * 64) * 16;
  }

  // ---- fragment LDS byte offsets (ks=0; ks=1 toggles ^64) ----
  int aoff[8], boffB[4];
  #pragma unroll
  for (int i = 0; i < 8; ++i) {
    int row = wm * 128 + i * 16 + fl;
    aoff[i] = (row * 8 + (q ^ (row & 7))) * 16;
  }
  #pragma unroll
  for (int i = 0; i < 4; ++i) {
    int row = wn * 64 + i * 16 + fl;
    boffB[i] = (row * 8 + (q ^ (row & 7))) * 16;   // relative to B buffer base
  }

  floatx4 zero = {0.f, 0.f, 0.f, 0.f};
  floatx4 acc[8][4];
  #pragma unroll
  for (int i = 0; i < 8; ++i)
    #pragma unroll
    for (int j = 0; j < 4; ++j) acc[i][j] = zero;

  const int NIT = K >> 6;                 // K-tiles of 64

  if constexpr (A_F32) {
    const float* Af = (const float*)Asel + (size_t)abz * sAb + kbase;
    // linear phys-slot ownership: slot j = n*512 + tid
    const float* gAs[4]; int wOff[4];
    #pragma unroll
    for (int n = 0; n < 4; ++n) {
      int j = n * 512 + tid;
      int row = j >> 3, c = (j & 7) ^ (row & 7);
      gAs[n] = Af + (size_t)(bm0 + row) * ldA + c * 8;
      wOff[n] = j * 16;
    }

    auto ABUF = [&](int i) -> char* { return smem + (i & 1) * 32768; };
    auto BBUF = [&](int i) -> char* { return smem + 65536 + (i % 3) * 32768; };

    float4 Ar[8];                         // single full A-tile bank (32 VGPR)
    auto aloadFull = [&](int k0) {
      #pragma unroll
      for (int n = 0; n < 4; ++n) {
        Ar[2 * n]     = *(const float4*)(gAs[n] + k0);
        Ar[2 * n + 1] = *(const float4*)(gAs[n] + k0 + 4);
      }
    };
    auto awriteFull = [&](char* base) {
      #pragma unroll
      for (int n = 0; n < 4; ++n)
        *(short8*)(base + wOff[n]) = cvt2(Ar[2 * n], Ar[2 * n + 1]);
    };
    auto stageB3 = [&](int k0, char* bbase) {
      #pragma unroll
      for (int n = 0; n < 4; ++n) gl_lds16(gB[n] + k0, bbase + sLo[n]);
    };

    short8 aF[4], bF[4];
    auto rdB = [&](const char* bbase, int ks) {
      #pragma unroll
      for (int i = 0; i < 4; ++i) bF[i] = *(const short8*)(bbase + (boffB[i] ^ (ks * 64)));
    };
    auto rdA = [&](const char* abase, int mh, int ks) {
      #pragma unroll
      for (int i = 0; i < 4; ++i) aF[i] = *(const short8*)(abase + (aoff[mh * 4 + i] ^ (ks * 64)));
    };
    auto mma = [&](int mh) {
      __builtin_amdgcn_s_setprio(1);
      #pragma unroll
      for (int i = 0; i < 4; ++i)
        #pragma unroll
        for (int ni = 0; ni < 4; ++ni)
          acc[mh * 4 + i][ni] =
              __builtin_amdgcn_mfma_f32_16x16x32_bf16(aF[i], bF[ni], acc[mh * 4 + i][ni], 0, 0, 0);
      __builtin_amdgcn_s_setprio(0);
    };

    // prologue (NIT >= 2 for all our shapes)
    aloadFull(0);                                       // A(0): 8
    stageB3(0, BBUF(0));                                // B(0): +4
    if (NIT > 1) stageB3(64, BBUF(1));                  // B(1): +4
    asm volatile("s_waitcnt vmcnt(8)" ::: "memory");    // A(0) landed
    awriteFull(ABUF(0));
    if (NIT > 1) aloadFull(64);                         // A(1): +8
    asm volatile("s_waitcnt vmcnt(12)" ::: "memory");   // B(0) landed
    asm volatile("s_waitcnt lgkmcnt(0)" ::: "memory");  // A(0) writes committed
    wg_barrier();                                       // tile 0 published

    for (int it = 0; it < NIT; ++it) {
      const char* Ab = ABUF(it);
      const char* Bb = BBUF(it);
      const bool pre1 = (it + 1 < NIT), pre2 = (it + 2 < NIT);
      if (pre2) stageB3((it + 2) * 64, BBUF(it + 2));
      // ---- ks = 0 ----
      rdB(Bb, 0);
      rdA(Ab, 0, 0); mma(0);
      rdA(Ab, 1, 0); mma(1);
      if (pre1) {
        if (pre2) { asm volatile("s_waitcnt vmcnt(4)" ::: "memory"); }  // A(it+1)+B(it+1) landed
        else      { asm volatile("s_waitcnt vmcnt(0)" ::: "memory"); }  // tail drain
        awriteFull(ABUF(it + 1));          // bank freed ...
        if (pre2) aloadFull((it + 2) * 64);// ... and refilled for it+2
      }
      // ---- ks = 1 ----
      rdB(Bb, 1);
      rdA(Ab, 0, 1); mma(0);
      rdA(Ab, 1, 1); mma(1);
      if (pre1) { asm volatile("s_waitcnt lgkmcnt(0)" ::: "memory"); }  // A-writes committed
      wg_barrier();                        // publish tile it+1; WAR
    }
  } else {
    // round-4 verified bf16 path: A via gl_lds, counted vmcnt(8), 2x64K buffers
    const u16* Ah = (const u16*)Asel + (size_t)abz * sAb + kbase;
    const u16* gA[4];
    #pragma unroll
    for (int n = 0; n < 4; ++n) {
      int j = n * 512 + tid;
      int row = j >> 3, pc = j & 7, c = pc ^ (row & 7);
      gA[n] = Ah + (size_t)(bm0 + row) * ldA + c * 8;
    }
    auto stage = [&](int k0, char* base) {
      #pragma unroll
      for (int n = 0; n < 4; ++n) gl_lds16(gA[n] + k0, base + sLo[n]);
      #pragma unroll
      for (int n = 0; n < 4; ++n) gl_lds16(gB[n] + k0, base + BOFF + sLo[n]);
    };
    auto compute = [&](const char* base) {
      #pragma unroll
      for (int ks = 0; ks < 2; ++ks) {
        short8 aF[8], bF[4];
        #pragma unroll
        for (int i = 0; i < 8; ++i) aF[i] = *(const short8*)(base + (aoff[i] ^ (ks * 64)));
        #pragma unroll
        for (int i = 0; i < 4; ++i) bF[i] = *(const short8*)(base + BOFF + (boffB[i] ^ (ks * 64)));
        __builtin_amdgcn_s_setprio(1);
        #pragma unroll
        for (int mi = 0; mi < 8; ++mi)
          #pragma unroll
          for (int ni = 0; ni < 4; ++ni)
            acc[mi][ni] = __builtin_amdgcn_mfma_f32_16x16x32_bf16(aF[mi], bF[ni], acc[mi][ni], 0, 0, 0);
        __builtin_amdgcn_s_setprio(0);
      }
    };
    stage(0, smem);
    for (int it = 0; it < NIT; ++it) {
      if (it + 1 < NIT) {
        stage((it + 1) * 64, smem + ((it + 1) & 1) * STRIDE);
        asm volatile("s_waitcnt vmcnt(8)" ::: "memory");
      } else {
        asm volatile("s_waitcnt vmcnt(0)" ::: "memory");
      }
      wg_barrier();
      compute(smem + (it & 1) * STRIDE);
      if (it + 1 < NIT) wg_barrier();
    }
  }

  if constexpr (!TRANS_OUT) {
    #pragma unroll
    for (int mi = 0; mi < 8; ++mi) {
      #pragma unroll
      for (int ni = 0; ni < 4; ++ni) {
        int col = bn0 + wn * 64 + ni * 16 + fl;
        #pragma unroll
        for (int r = 0; r < 4; ++r) {
          int row = bm0 + wm * 128 + mi * 16 + r4 + r;
          float vv = acc[mi][ni][r];
          if constexpr (EPI == EPI_PHI_BIAS) {
            vv += biasSel[col];
            if (phi_on) vv = __expf(-0.5f * vv * vv);
          }
          if constexpr (EPI == EPI_BIAS || EPI == EPI_BIAS_F32) vv += biasSel[col];
          if constexpr (EPI == EPI_ZSCALE) vv *= Zall[(size_t)abz * sZb + row];
          if constexpr (EPI == EPI_ZBIAS_F32)
            vv = vv * Zall[(size_t)abz * sZb + row] + biasSel[col];
          if constexpr (EPI == EPI_BIAS_F32 || EPI == EPI_ZBIAS_F32)
            ((float*)Csel)[(size_t)bz * sCb + (size_t)row * ldC + col] = vv;
          else
            ((u16*)Csel)[(size_t)bz * sCb + (size_t)row * ldC + col] = f2b(vv);
        }
      }
    }
  } else {
    // transpose through LDS in two 128-t-row passes, then coalesced 16B
    // stores into [4][N][4096]. sT = [256 d][136 t-pad] u16 = 69632 B.
    float ks[4] = {0.f, 0.f, 0.f, 0.f};   // fused Ksum column partials
    __syncthreads();                      // all compute reads done, smem free
    u16* sT = (u16*)smem;
    #pragma unroll
    for (int h = 0; h < 2; ++h) {
      if (wm == h) {
        #pragma unroll
        for (int mi = 0; mi < 8; ++mi) {
          #pragma unroll
          for (int ni = 0; ni < 4; ++ni) {
            int colL = wn * 64 + ni * 16 + fl;
            int row0 = mi * 16 + r4;
            float bcol = biasSel[bn0 + colL];
            ushort4 hh;
            #pragma unroll
            for (int r = 0; r < 4; ++r) {
              float vv = acc[mi][ni][r] + bcol;
              if (phi_on) vv = __expf(-0.5f * vv * vv);
              if constexpr (DUAL) ks[ni] += vv;
              ((u16*)&hh)[r] = f2b(vv);
            }
            *(ushort4*)(sT + colL * 136 + row0) = hh;
          }
        }
      }
      __syncthreads();
      #pragma unroll
      for (int i = 0; i < 8; ++i) {
        int c = i * 512 + tid;            // 4096 x 16B chunks (256 d x 128 t)
        int dloc = c >> 4, t16 = (c & 15) * 8;
        int4 vv = *(const int4*)(sT + dloc * 136 + t16);
        int gd = bn0 + dloc;
        int gt = bm0 + h * 128 + t16;
        int batch = gt >> 12, tt = gt & 4095;
        *(int4*)((u16*)Csel + ((size_t)batch * N + gd) * 4096 + tt) = vv;
      }
      __syncthreads();
    }
    if constexpr (DUAL) {
      if (phi_on) {                       // K-projection blocks: fused Ksum
        #pragma unroll
        for (int ni = 0; ni < 4; ++ni) {
          float s = ks[ni];
          s += __shfl_xor(s, 16, 64);
          s += __shfl_xor(s, 32, 64);
          if (q == 0)
            atomicAdd(ksum_out + ((bm0 >> 12) << 10) + bn0 + wn * 64 + ni * 16 + fl, s);
        }
      }
    }
  }
}

__global__ __launch_bounds__(256)
void wconv(const float* __restrict__ w0, const float* __restrict__ w1,
           const float* __restrict__ w2, const float* __restrict__ w3,
           u16* __restrict__ dst, float* __restrict__ ksum) {
  if (blockIdx.x == 0) {                 // zero Ksum [4][1024] for fused atomics
    float4 z = {0.f, 0.f, 0.f, 0.f};
    #pragma unroll
    for (int i = 0; i < 4; ++i)
      *(float4*)(ksum + threadIdx.x * 16 + i * 4) = z;
  }
  unsigned e = blockIdx.x * 256 + threadIdx.x;
  int mat = e >> 18;
  size_t off = (size_t)(e & 262143) * 4;
  const float* src = mat == 0 ? w0 : mat == 1 ? w1 : mat == 2 ? w2 : w3;
  float4 v = *(const float4*)(src + off);
  ushort4 h;
  h.x = f2b(v.x); h.y = f2b(v.y); h.z = f2b(v.z); h.w = f2b(v.w);
  *(ushort4*)(dst + (size_t)mat * 1048576 + off) = h;
}

// out[i] = round(sum over 4 K-slices of bf16 partials), 4M elems, slice stride 4M
__global__ __launch_bounds__(256)
void reduce4(const u16* __restrict__ P, u16* __restrict__ out) {
  size_t i = ((size_t)blockIdx.x * 256 + threadIdx.x) * 8;
  int4 a = *(const int4*)(P + i);
  int4 b = *(const int4*)(P + i + 4194304);
  int4 c = *(const int4*)(P + i + 8388608);
  int4 d = *(const int4*)(P + i + 12582912);
  const u16* ha = (const u16*)&a; const u16* hb = (const u16*)&b;
  const u16* hc = (const u16*)&c; const u16* hd = (const u16*)&d;
  ushort4 o0, o1;
  #pragma unroll
  for (int j = 0; j < 8; ++j) {
    float s = b2f(ha[j]) + b2f(hb[j]) + b2f(hc[j]) + b2f(hd[j]);
    ((u16*)(j < 4 ? &o0 : &o1))[j & 3] = f2b(s);
  }
  *(ushort4*)(out + i) = o0;
  *(ushort4*)(out + i + 4) = o1;
}

// Z[t] = 1/(Q[t,:]·Ksum[batch,:] + 1e-6); one wave per token
__global__ __launch_bounds__(256)
void zden(const u16* __restrict__ Qb, const float* __restrict__ Ksum,
          float* __restrict__ Z) {
  int lane = threadIdx.x & 63;
  int t = blockIdx.x * 4 + (threadIdx.x >> 6);
  const u16* qp = Qb + (size_t)t * 1024;
  const float* ks = Ksum + (size_t)(t >> 12) * 1024;
  float s = 0.f;
  #pragma unroll
  for (int i = 0; i < 2; ++i) {
    int idx = i * 512 + lane * 8;
    int4 d = *(const int4*)(qp + idx);
    const u16* h = (const u16*)&d;
    float4 k0 = *(const float4*)(ks + idx);
    float4 k1 = *(const float4*)(ks + idx + 4);
    s += b2f(h[0]) * k0.x + b2f(h[1]) * k0.y + b2f(h[2]) * k0.z + b2f(h[3]) * k0.w
       + b2f(h[4]) * k1.x + b2f(h[5]) * k1.y + b2f(h[6]) * k1.z + b2f(h[7]) * k1.w;
  }
  #pragma unroll
  for (int off = 32; off; off >>= 1) s += __shfl_xor(s, off, 64);
  if (lane == 0) Z[t] = 1.0f / (s + 1e-6f);
}

extern "C" void kernel_launch(void* const* d_in, const int* in_sizes, int n_in,
                              void* d_out, int out_size, void* d_ws, size_t ws_size,
                              hipStream_t stream) {
  const float* q  = (const float*)d_in[0];
  const float* k  = (const float*)d_in[1];
  const float* v  = (const float*)d_in[2];
  const float* Wq = (const float*)d_in[3];
  const float* bq = (const float*)d_in[4];
  const float* Wk = (const float*)d_in[5];
  const float* bk = (const float*)d_in[6];
  const float* Wv = (const float*)d_in[7];
  const float* bv = (const float*)d_in[8];
  const float* Wo = (const float*)d_in[9];
  const float* bo = (const float*)d_in[10];
  float* out = (float*)d_out;

  // workspace layout (~112.1 MiB) with aliasing:
  u16* Wqb = (u16*)d_ws;                 // 4x 1024x1024 bf16 = 8 MiB
  u16* Wkb = Wqb + 1048576;
  u16* Wvb = Wkb + 1048576;
  u16* Wob = Wvb + 1048576;
  u16* Qb  = Wob + 1048576;              // [16384][1024] bf16, 32 MiB
  u16* KT  = Qb  + 16777216;             // [4][1024][4096] bf16, 32 MiB
  u16* VT  = KT  + 16777216;             // [4][1024][4096] bf16, 32 MiB
  u16* KVr = VT  + 16777216;             // [4][1024(d)][1024(l)] bf16, 8 MiB
  float* Ksum = (float*)(KVr + 4194304); // [4][1024] f32 (atomically built)
  float* Z    = Ksum + 4096;             // [16384] f32
  u16* Pkv = Qb;   // S2 split-K partials, before Q-proj overwrites
  u16* Pg  = VT;   // G split-K partials, after VT dead
  u16* Gp  = KT;   // G' [4][1024(n)][1024(d)], after KT dead

  constexpr size_t LDS_BF16 = 131072;    // 2 x (A32K + B32K)
  constexpr size_t LDS_F32  = 163840;    // A 2x32K + B 3x32K (full 160K)

  wconv<<<4096, 256, 0, stream>>>(Wq, Wk, Wv, Wo, Wqb, Ksum);

  // K,V projections in ONE dispatch (grid z: 0=K with phi + fused Ksum,
  // 1=V bias-only). A = fp32 k / v directly (in-kernel conversion).
  dim3 gkv(64, 4, 2);
  gemm_bt<EPI_PHI_BIAS, true, true, true><<<gkv, 512, LDS_F32, stream>>>(
      k, Wkb, bk, nullptr, KT, 16384, 1024, 1024, 1024, 1024, 0,
      0, 0, 0, 0, 0, 30, v, Wvb, bv, VT, Ksum);

  // S2: KVr[d,l] = sum_t KT[d,t]*VT[l,t], split-K x4 (z = kslice*4+batch)
  dim3 g2(4, 4, 16);
  gemm_bt<EPI_NONE, false, false, false><<<g2, 512, LDS_BF16, stream>>>(
      KT, VT, nullptr, nullptr, Pkv, 1024, 1024, 1024, 4096, 4096, 1024,
      4194304L, 4194304L, 1048576L, 0, 3, 2, nullptr, nullptr, nullptr, nullptr, nullptr);
  reduce4<<<2048, 256, 0, stream>>>(Pkv, KVr);

  // Q projection from fp32 q (overwrites partials region — stream-ordered)
  dim3 g1(64, 4, 1);
  gemm_bt<EPI_PHI_BIAS, true, false, false><<<g1, 512, LDS_F32, stream>>>(
      q, Wqb, bq, nullptr, Qb, 16384, 1024, 1024, 1024, 1024, 1024,
      0, 0, 0, 0, 0, 30, nullptr, nullptr, nullptr, nullptr, nullptr);

  zden<<<4096, 256, 0, stream>>>(Qb, Ksum, Z);

  // G'[n,d] = sum_l Wob[n,l]*KVr[d,l], split-K x4 (K=256/slice); Wo folded in.
  dim3 gg(4, 4, 16);
  gemm_bt<EPI_NONE, false, false, false><<<gg, 512, LDS_BF16, stream>>>(
      Wob, KVr, nullptr, nullptr, Pg, 1024, 1024, 256, 1024, 1024, 1024,
      0L, 1048576L, 1048576L, 0, 3, 2, nullptr, nullptr, nullptr, nullptr, nullptr);
  reduce4<<<2048, 256, 0, stream>>>(Pg, Gp);

  // final: out[t,n] = Z[t]*(sum_d Qb[t,d]*G'[n,d]) + bo[n], fp32 out
  dim3 gf(16, 4, 4);
  gemm_bt<EPI_ZBIAS_F32, false, false, false><<<gf, 512, LDS_BF16, stream>>>(
      Qb, Gp, bo, Z, out, 4096, 1024, 1024, 1024, 1024, 1024,
      4194304L, 1048576L, 4194304L, 4096L, 3, 30, nullptr, nullptr, nullptr, nullptr, nullptr);
}

// Round 14
// 414.884 us; speedup vs baseline: 1.0948x; 1.0013x over previous
//
#include <hip/hip_runtime.h>

typedef unsigned short u16;
typedef unsigned int u32;
typedef unsigned long long u64;

typedef __attribute__((ext_vector_type(8))) short short8;   // 8 bf16 = 4 VGPRs
typedef __attribute__((ext_vector_type(4))) float floatx4;  // MFMA accumulator

__device__ __forceinline__ float b2f(u16 h) {
  u32 u = ((u32)h) << 16;
  return __builtin_bit_cast(float, u);
}
__device__ __forceinline__ u16 f2b(float f) {
  u32 u = __builtin_bit_cast(u32, f);
  u32 r = 0x7FFFu + ((u >> 16) & 1u);  // RNE
  return (u16)((u + r) >> 16);
}

// async global->LDS, 16B per lane. LDS dest = wave-uniform base + lane*16.
__device__ __forceinline__ void gl_lds16(const void* g, void* l) {
  __builtin_amdgcn_global_load_lds(
      (__attribute__((address_space(1))) void*)(u64)g,
      (__attribute__((address_space(3))) void*)(u32)(u64)l, 16, 0, 0);
}

// raw workgroup barrier WITHOUT the compiler's vmcnt(0) drain, so
// global_load_lds prefetches stay in flight across it.
__device__ __forceinline__ void wg_barrier() {
  asm volatile("" ::: "memory");
  __builtin_amdgcn_s_barrier();
  asm volatile("" ::: "memory");
}

// trunc-pack 8 fp32 -> 8 bf16 (verified byte order, round-0 kernel)
__device__ __forceinline__ short8 cvt2(const float4& a, const float4& b) {
  union { u32 w[4]; short8 s; } cv;
  const u32* x = (const u32*)&a;
  const u32* y = (const u32*)&b;
  cv.w[0] = __builtin_amdgcn_perm(x[1], x[0], 0x07060302u);
  cv.w[1] = __builtin_amdgcn_perm(x[3], x[2], 0x07060302u);
  cv.w[2] = __builtin_amdgcn_perm(y[1], y[0], 0x07060302u);
  cv.w[3] = __builtin_amdgcn_perm(y[3], y[2], 0x07060302u);
  return cv.s;
}

enum { EPI_PHI_BIAS = 0, EPI_BIAS = 1, EPI_NONE = 2, EPI_ZSCALE = 3,
       EPI_BIAS_F32 = 4, EPI_ZBIAS_F32 = 5 };

// C[m,n] = sum_k A[m,k] * B[n,k]  (K-contiguous). 256x256x64 tile, 8 waves
// (2M x 4N, 128x64 per wave). Per-dispatch rocprof timings swing ±30% across
// runs — judge by totals.
//
// A_F32 (round-13, VERIFIED): deep-in-time pipeline, 160K LDS (A dbuf 2x32K,
// B tribuf 3x32K), single 32-VGPR A bank, loads in flight >= 1 iter before
// their wait, ONE barrier/iter, no vmem drain in steady loop.
//
// bf16 path (round-14): SAME mechanism ported. A dbuf 2x32K @0 staged 1
// ahead, B tribuf 3x32K @64K staged 2 ahead, BOTH staged AFTER the barrier
// => every staged buffer's last read precedes the previous barrier (WAR via
// the single per-iter barrier; R4's second barrier eliminated). Pre-barrier
// counted wait vmcnt(it+1<NIT ? 4 : 0) keeps only B(it+1) in flight and
// drains {A(it), B(it)}:
//   A(it): issued post-BAR(it-1) -> cover = compute(it-1) (1 phase, same as
//          R4); B(it): issued post-BAR(it-2) -> 2-phase cover.
//   FIFO walk (issue order A then B each iter) verified for it=0,1,steady,
//   tails: drained set always exactly {needed}, kept set = B(it+1) only.
//   Prologue stages A(0),B(0),B(1); first vmcnt(4) is the only short-cover
//   wait (one-time ~900cy).
//   Per-wave counters + barrier => cross-wave validity (round-3 lesson).
// Halves the bf16 barrier count at unchanged wait cover — attacks the
// 2-barrier lockstep tax (m233) on S2/G'/final.
// LDS layout per buffer: [256 rows][8 slots of 16B], phys slot = c^(row&7)
// (conflict-free ds_read_b128). Lane-linear phys-slot ownership for fp32 A
// writes (one LDS row = 128B = full bank wrap => only lane-linear is clean).
// Block swizzle: XCD-chunked remap, N-tiles of one M-slab adjacent.
// gridDim.y==4, (gx*gy)%8==0 for all launches.
// Split-K: blockIdx.z = kslice*(abmask+1)+batch.
// DUAL: bz selects operand set 1 (A2/B2/bias2/C2, no phi) vs set 0 (phi).
// KSUM (DUAL && TRANS_OUT && phi_on): epilogue column sums of the phi'd tile
// atomicAdd into ksum_out[batch*1024+col] (fused Ksum).
template<int EPI, bool A_F32, bool TRANS_OUT, bool DUAL>
__global__ __launch_bounds__(512, 2)
void gemm_bt(const void* __restrict__ Aall, const u16* __restrict__ Ball,
             const float* __restrict__ bias, const float* __restrict__ Zall,
             void* __restrict__ Call,
             int M, int N, int K, int ldA, int ldB, int ldC,
             long sAb, long sBb, long sCb, long sZb, int abmask, int kshift,
             const void* __restrict__ Aall2, const u16* __restrict__ Ball2,
             const float* __restrict__ bias2, void* __restrict__ Call2,
             float* __restrict__ ksum_out)
{
  extern __shared__ char smem[];

  const int tid  = threadIdx.x;
  const int lane = tid & 63;
  const int wave = tid >> 6;
  const int wm = wave >> 2, wn = wave & 3;   // 2x4 waves, 128x64 each
  const int fl = lane & 15;
  const int q  = lane >> 4;
  const int r4 = q * 4;

  // XCD-chunked block swizzle; consecutive remapped ids iterate the 4 N-tiles
  // of one M-tile.
  const int orig = blockIdx.x + gridDim.x * blockIdx.y;
  const int nwg8 = (gridDim.x * gridDim.y) >> 3;
  const int wsw  = (orig & 7) * nwg8 + (orig >> 3);
  const int bm0 = (wsw >> 2) * 256;          // gridDim.y == 4 in all launches
  const int bn0 = (wsw & 3) * 256;

  const int bz = blockIdx.z;
  const int abz = bz & abmask;
  const int kbase = (bz >> kshift) * K;

  const void* Asel = Aall; const u16* Bsel = Ball;
  const float* biasSel = bias; void* Csel = Call;
  bool phi_on = true;
  if constexpr (DUAL) {
    if (bz) { Asel = Aall2; Bsel = Ball2; biasSel = bias2; Csel = Call2; phi_on = false; }
  }

  const u16* Bp = Bsel + (size_t)abz * sBb + kbase;

  // ---- B staging addresses (global per-lane pre-swizzled; LDS dest linear) --
  const u16* gB[4]; int sLo[4];
  #pragma unroll
  for (int n = 0; n < 4; ++n) {
    int j = n * 512 + tid;
    int row = j >> 3, pc = j & 7, c = pc ^ (row & 7);
    gB[n] = Bp + (size_t)(bn0 + row) * ldB + c * 8;
    sLo[n] = (n * 512 + wave * 64) * 16;
  }

  // ---- fragment LDS byte offsets (ks=0; ks=1 toggles ^64) ----
  int aoff[8], boffB[4];
  #pragma unroll
  for (int i = 0; i < 8; ++i) {
    int row = wm * 128 + i * 16 + fl;
    aoff[i] = (row * 8 + (q ^ (row & 7))) * 16;
  }
  #pragma unroll
  for (int i = 0; i < 4; ++i) {
    int row = wn * 64 + i * 16 + fl;
    boffB[i] = (row * 8 + (q ^ (row & 7))) * 16;   // relative to buffer base
  }

  floatx4 zero = {0.f, 0.f, 0.f, 0.f};
  floatx4 acc[8][4];
  #pragma unroll
  for (int i = 0; i < 8; ++i)
    #pragma unroll
    for (int j = 0; j < 4; ++j) acc[i][j] = zero;

  const int NIT = K >> 6;                 // K-tiles of 64

  auto ABUF = [&](int i) -> char* { return smem + (i & 1) * 32768; };
  auto BBUF = [&](int i) -> char* { return smem + 65536 + (i % 3) * 32768; };
  auto stageB3 = [&](int k0, char* bbase) {
    #pragma unroll
    for (int n = 0; n < 4; ++n) gl_lds16(gB[n] + k0, bbase + sLo[n]);
  };

  if constexpr (A_F32) {
    const float* Af = (const float*)Asel + (size_t)abz * sAb + kbase;
    // linear phys-slot ownership: slot j = n*512 + tid
    const float* gAs[4]; int wOff[4];
    #pragma unroll
    for (int n = 0; n < 4; ++n) {
      int j = n * 512 + tid;
      int row = j >> 3, c = (j & 7) ^ (row & 7);
      gAs[n] = Af + (size_t)(bm0 + row) * ldA + c * 8;
      wOff[n] = j * 16;
    }

    float4 Ar[8];                         // single full A-tile bank (32 VGPR)
    auto aloadFull = [&](int k0) {
      #pragma unroll
      for (int n = 0; n < 4; ++n) {
        Ar[2 * n]     = *(const float4*)(gAs[n] + k0);
        Ar[2 * n + 1] = *(const float4*)(gAs[n] + k0 + 4);
      }
    };
    auto awriteFull = [&](char* base) {
      #pragma unroll
      for (int n = 0; n < 4; ++n)
        *(short8*)(base + wOff[n]) = cvt2(Ar[2 * n], Ar[2 * n + 1]);
    };

    short8 aF[4], bF[4];
    auto rdB = [&](const char* bbase, int ks) {
      #pragma unroll
      for (int i = 0; i < 4; ++i) bF[i] = *(const short8*)(bbase + (boffB[i] ^ (ks * 64)));
    };
    auto rdA = [&](const char* abase, int mh, int ks) {
      #pragma unroll
      for (int i = 0; i < 4; ++i) aF[i] = *(const short8*)(abase + (aoff[mh * 4 + i] ^ (ks * 64)));
    };
    auto mma = [&](int mh) {
      __builtin_amdgcn_s_setprio(1);
      #pragma unroll
      for (int i = 0; i < 4; ++i)
        #pragma unroll
        for (int ni = 0; ni < 4; ++ni)
          acc[mh * 4 + i][ni] =
              __builtin_amdgcn_mfma_f32_16x16x32_bf16(aF[i], bF[ni], acc[mh * 4 + i][ni], 0, 0, 0);
      __builtin_amdgcn_s_setprio(0);
    };

    // prologue (NIT >= 2 for all our shapes)
    aloadFull(0);                                       // A(0): 8
    stageB3(0, BBUF(0));                                // B(0): +4
    if (NIT > 1) stageB3(64, BBUF(1));                  // B(1): +4
    asm volatile("s_waitcnt vmcnt(8)" ::: "memory");    // A(0) landed
    awriteFull(ABUF(0));
    if (NIT > 1) aloadFull(64);                         // A(1): +8
    asm volatile("s_waitcnt vmcnt(12)" ::: "memory");   // B(0) landed
    asm volatile("s_waitcnt lgkmcnt(0)" ::: "memory");  // A(0) writes committed
    wg_barrier();                                       // tile 0 published

    for (int it = 0; it < NIT; ++it) {
      const char* Ab = ABUF(it);
      const char* Bb = BBUF(it);
      const bool pre1 = (it + 1 < NIT), pre2 = (it + 2 < NIT);
      if (pre2) stageB3((it + 2) * 64, BBUF(it + 2));
      // ---- ks = 0 ----
      rdB(Bb, 0);
      rdA(Ab, 0, 0); mma(0);
      rdA(Ab, 1, 0); mma(1);
      if (pre1) {
        if (pre2) { asm volatile("s_waitcnt vmcnt(4)" ::: "memory"); }  // A(it+1)+B(it+1) landed
        else      { asm volatile("s_waitcnt vmcnt(0)" ::: "memory"); }  // tail drain
        awriteFull(ABUF(it + 1));          // bank freed ...
        if (pre2) aloadFull((it + 2) * 64);// ... and refilled for it+2
      }
      // ---- ks = 1 ----
      rdB(Bb, 1);
      rdA(Ab, 0, 1); mma(0);
      rdA(Ab, 1, 1); mma(1);
      if (pre1) { asm volatile("s_waitcnt lgkmcnt(0)" ::: "memory"); }  // A-writes committed
      wg_barrier();                        // publish tile it+1; WAR
    }
  } else {
    // round-14 bf16 path: single-barrier deep pipeline (mechanism = R13).
    // A via gl_lds staged 1 ahead (dbuf), B staged 2 ahead (tribuf); all
    // stages AFTER the barrier; pre-barrier vmcnt keeps only B(it+1).
    const u16* Ah = (const u16*)Asel + (size_t)abz * sAb + kbase;
    const u16* gA[4];
    #pragma unroll
    for (int n = 0; n < 4; ++n) {
      int j = n * 512 + tid;
      int row = j >> 3, pc = j & 7, c = pc ^ (row & 7);
      gA[n] = Ah + (size_t)(bm0 + row) * ldA + c * 8;
    }
    auto stageA = [&](int k0, char* abase) {
      #pragma unroll
      for (int n = 0; n < 4; ++n) gl_lds16(gA[n] + k0, abase + sLo[n]);
    };
    auto compute = [&](const char* Ab, const char* Bb) {
      #pragma unroll
      for (int ks = 0; ks < 2; ++ks) {
        short8 aF[8], bF[4];
        #pragma unroll
        for (int i = 0; i < 8; ++i) aF[i] = *(const short8*)(Ab + (aoff[i] ^ (ks * 64)));
        #pragma unroll
        for (int i = 0; i < 4; ++i) bF[i] = *(const short8*)(Bb + (boffB[i] ^ (ks * 64)));
        __builtin_amdgcn_s_setprio(1);
        #pragma unroll
        for (int mi = 0; mi < 8; ++mi)
          #pragma unroll
          for (int ni = 0; ni < 4; ++ni)
            acc[mi][ni] = __builtin_amdgcn_mfma_f32_16x16x32_bf16(aF[mi], bF[ni], acc[mi][ni], 0, 0, 0);
        __builtin_amdgcn_s_setprio(0);
      }
    };
    // prologue: A(0), B(0), B(1) — first wait is the only short-cover one.
    stageA(0, ABUF(0));
    stageB3(0, BBUF(0));
    if (NIT > 1) stageB3(64, BBUF(1));
    for (int it = 0; it < NIT; ++it) {
      if (it + 1 < NIT) { asm volatile("s_waitcnt vmcnt(4)" ::: "memory"); }  // keep B(it+1); A(it),B(it) landed
      else              { asm volatile("s_waitcnt vmcnt(0)" ::: "memory"); }
      wg_barrier();                        // publish tile it (RAW); WAR gate
      if (it + 1 < NIT) stageA((it + 1) * 64, ABUF(it + 1));
      if (it + 2 < NIT) stageB3((it + 2) * 64, BBUF(it + 2));
      compute(ABUF(it), BBUF(it));
    }
  }

  if constexpr (!TRANS_OUT) {
    #pragma unroll
    for (int mi = 0; mi < 8; ++mi) {
      #pragma unroll
      for (int ni = 0; ni < 4; ++ni) {
        int col = bn0 + wn * 64 + ni * 16 + fl;
        #pragma unroll
        for (int r = 0; r < 4; ++r) {
          int row = bm0 + wm * 128 + mi * 16 + r4 + r;
          float vv = acc[mi][ni][r];
          if constexpr (EPI == EPI_PHI_BIAS) {
            vv += biasSel[col];
            if (phi_on) vv = __expf(-0.5f * vv * vv);
          }
          if constexpr (EPI == EPI_BIAS || EPI == EPI_BIAS_F32) vv += biasSel[col];
          if constexpr (EPI == EPI_ZSCALE) vv *= Zall[(size_t)abz * sZb + row];
          if constexpr (EPI == EPI_ZBIAS_F32)
            vv = vv * Zall[(size_t)abz * sZb + row] + biasSel[col];
          if constexpr (EPI == EPI_BIAS_F32 || EPI == EPI_ZBIAS_F32)
            ((float*)Csel)[(size_t)bz * sCb + (size_t)row * ldC + col] = vv;
          else
            ((u16*)Csel)[(size_t)bz * sCb + (size_t)row * ldC + col] = f2b(vv);
        }
      }
    }
  } else {
    // transpose through LDS in two 128-t-row passes, then coalesced 16B
    // stores into [4][N][4096]. sT = [256 d][136 t-pad] u16 = 69632 B.
    float ks[4] = {0.f, 0.f, 0.f, 0.f};   // fused Ksum column partials
    __syncthreads();                      // all compute reads done, smem free
    u16* sT = (u16*)smem;
    #pragma unroll
    for (int h = 0; h < 2; ++h) {
      if (wm == h) {
        #pragma unroll
        for (int mi = 0; mi < 8; ++mi) {
          #pragma unroll
          for (int ni = 0; ni < 4; ++ni) {
            int colL = wn * 64 + ni * 16 + fl;
            int row0 = mi * 16 + r4;
            float bcol = biasSel[bn0 + colL];
            ushort4 hh;
            #pragma unroll
            for (int r = 0; r < 4; ++r) {
              float vv = acc[mi][ni][r] + bcol;
              if (phi_on) vv = __expf(-0.5f * vv * vv);
              if constexpr (DUAL) ks[ni] += vv;
              ((u16*)&hh)[r] = f2b(vv);
            }
            *(ushort4*)(sT + colL * 136 + row0) = hh;
          }
        }
      }
      __syncthreads();
      #pragma unroll
      for (int i = 0; i < 8; ++i) {
        int c = i * 512 + tid;            // 4096 x 16B chunks (256 d x 128 t)
        int dloc = c >> 4, t16 = (c & 15) * 8;
        int4 vv = *(const int4*)(sT + dloc * 136 + t16);
        int gd = bn0 + dloc;
        int gt = bm0 + h * 128 + t16;
        int batch = gt >> 12, tt = gt & 4095;
        *(int4*)((u16*)Csel + ((size_t)batch * N + gd) * 4096 + tt) = vv;
      }
      __syncthreads();
    }
    if constexpr (DUAL) {
      if (phi_on) {                       // K-projection blocks: fused Ksum
        #pragma unroll
        for (int ni = 0; ni < 4; ++ni) {
          float s = ks[ni];
          s += __shfl_xor(s, 16, 64);
          s += __shfl_xor(s, 32, 64);
          if (q == 0)
            atomicAdd(ksum_out + ((bm0 >> 12) << 10) + bn0 + wn * 64 + ni * 16 + fl, s);
        }
      }
    }
  }
}

__global__ __launch_bounds__(256)
void wconv(const float* __restrict__ w0, const float* __restrict__ w1,
           const float* __restrict__ w2, const float* __restrict__ w3,
           u16* __restrict__ dst, float* __restrict__ ksum) {
  if (blockIdx.x == 0) {                 // zero Ksum [4][1024] for fused atomics
    float4 z = {0.f, 0.f, 0.f, 0.f};
    #pragma unroll
    for (int i = 0; i < 4; ++i)
      *(float4*)(ksum + threadIdx.x * 16 + i * 4) = z;
  }
  unsigned e = blockIdx.x * 256 + threadIdx.x;
  int mat = e >> 18;
  size_t off = (size_t)(e & 262143) * 4;
  const float* src = mat == 0 ? w0 : mat == 1 ? w1 : mat == 2 ? w2 : w3;
  float4 v = *(const float4*)(src + off);
  ushort4 h;
  h.x = f2b(v.x); h.y = f2b(v.y); h.z = f2b(v.z); h.w = f2b(v.w);
  *(ushort4*)(dst + (size_t)mat * 1048576 + off) = h;
}

// out[i] = round(sum over 4 K-slices of bf16 partials), 4M elems, slice stride 4M
__global__ __launch_bounds__(256)
void reduce4(const u16* __restrict__ P, u16* __restrict__ out) {
  size_t i = ((size_t)blockIdx.x * 256 + threadIdx.x) * 8;
  int4 a = *(const int4*)(P + i);
  int4 b = *(const int4*)(P + i + 4194304);
  int4 c = *(const int4*)(P + i + 8388608);
  int4 d = *(const int4*)(P + i + 12582912);
  const u16* ha = (const u16*)&a; const u16* hb = (const u16*)&b;
  const u16* hc = (const u16*)&c; const u16* hd = (const u16*)&d;
  ushort4 o0, o1;
  #pragma unroll
  for (int j = 0; j < 8; ++j) {
    float s = b2f(ha[j]) + b2f(hb[j]) + b2f(hc[j]) + b2f(hd[j]);
    ((u16*)(j < 4 ? &o0 : &o1))[j & 3] = f2b(s);
  }
  *(ushort4*)(out + i) = o0;
  *(ushort4*)(out + i + 4) = o1;
}

// Z[t] = 1/(Q[t,:]·Ksum[batch,:] + 1e-6); one wave per token
__global__ __launch_bounds__(256)
void zden(const u16* __restrict__ Qb, const float* __restrict__ Ksum,
          float* __restrict__ Z) {
  int lane = threadIdx.x & 63;
  int t = blockIdx.x * 4 + (threadIdx.x >> 6);
  const u16* qp = Qb + (size_t)t * 1024;
  const float* ks = Ksum + (size_t)(t >> 12) * 1024;
  float s = 0.f;
  #pragma unroll
  for (int i = 0; i < 2; ++i) {
    int idx = i * 512 + lane * 8;
    int4 d = *(const int4*)(qp + idx);
    const u16* h = (const u16*)&d;
    float4 k0 = *(const float4*)(ks + idx);
    float4 k1 = *(const float4*)(ks + idx + 4);
    s += b2f(h[0]) * k0.x + b2f(h[1]) * k0.y + b2f(h[2]) * k0.z + b2f(h[3]) * k0.w
       + b2f(h[4]) * k1.x + b2f(h[5]) * k1.y + b2f(h[6]) * k1.z + b2f(h[7]) * k1.w;
  }
  #pragma unroll
  for (int off = 32; off; off >>= 1) s += __shfl_xor(s, off, 64);
  if (lane == 0) Z[t] = 1.0f / (s + 1e-6f);
}

extern "C" void kernel_launch(void* const* d_in, const int* in_sizes, int n_in,
                              void* d_out, int out_size, void* d_ws, size_t ws_size,
                              hipStream_t stream) {
  const float* q  = (const float*)d_in[0];
  const float* k  = (const float*)d_in[1];
  const float* v  = (const float*)d_in[2];
  const float* Wq = (const float*)d_in[3];
  const float* bq = (const float*)d_in[4];
  const float* Wk = (const float*)d_in[5];
  const float* bk = (const float*)d_in[6];
  const float* Wv = (const float*)d_in[7];
  const float* bv = (const float*)d_in[8];
  const float* Wo = (const float*)d_in[9];
  const float* bo = (const float*)d_in[10];
  float* out = (float*)d_out;

  // workspace layout (~112.1 MiB) with aliasing:
  u16* Wqb = (u16*)d_ws;                 // 4x 1024x1024 bf16 = 8 MiB
  u16* Wkb = Wqb + 1048576;
  u16* Wvb = Wkb + 1048576;
  u16* Wob = Wvb + 1048576;
  u16* Qb  = Wob + 1048576;              // [16384][1024] bf16, 32 MiB
  u16* KT  = Qb  + 16777216;             // [4][1024][4096] bf16, 32 MiB
  u16* VT  = KT  + 16777216;             // [4][1024][4096] bf16, 32 MiB
  u16* KVr = VT  + 16777216;             // [4][1024(d)][1024(l)] bf16, 8 MiB
  float* Ksum = (float*)(KVr + 4194304); // [4][1024] f32 (atomically built)
  float* Z    = Ksum + 4096;             // [16384] f32
  u16* Pkv = Qb;   // S2 split-K partials, before Q-proj overwrites
  u16* Pg  = VT;   // G split-K partials, after VT dead
  u16* Gp  = KT;   // G' [4][1024(n)][1024(d)], after KT dead

  constexpr size_t LDS_DEEP = 163840;    // A 2x32K + B 3x32K (full 160K)

  wconv<<<4096, 256, 0, stream>>>(Wq, Wk, Wv, Wo, Wqb, Ksum);

  // K,V projections in ONE dispatch (grid z: 0=K with phi + fused Ksum,
  // 1=V bias-only). A = fp32 k / v directly (in-kernel conversion).
  dim3 gkv(64, 4, 2);
  gemm_bt<EPI_PHI_BIAS, true, true, true><<<gkv, 512, LDS_DEEP, stream>>>(
      k, Wkb, bk, nullptr, KT, 16384, 1024, 1024, 1024, 1024, 0,
      0, 0, 0, 0, 0, 30, v, Wvb, bv, VT, Ksum);

  // S2: KVr[d,l] = sum_t KT[d,t]*VT[l,t], split-K x4 (z = kslice*4+batch)
  dim3 g2(4, 4, 16);
  gemm_bt<EPI_NONE, false, false, false><<<g2, 512, LDS_DEEP, stream>>>(
      KT, VT, nullptr, nullptr, Pkv, 1024, 1024, 1024, 4096, 4096, 1024,
      4194304L, 4194304L, 1048576L, 0, 3, 2, nullptr, nullptr, nullptr, nullptr, nullptr);
  reduce4<<<2048, 256, 0, stream>>>(Pkv, KVr);

  // Q projection from fp32 q (overwrites partials region — stream-ordered)
  dim3 g1(64, 4, 1);
  gemm_bt<EPI_PHI_BIAS, true, false, false><<<g1, 512, LDS_DEEP, stream>>>(
      q, Wqb, bq, nullptr, Qb, 16384, 1024, 1024, 1024, 1024, 1024,
      0, 0, 0, 0, 0, 30, nullptr, nullptr, nullptr, nullptr, nullptr);

  zden<<<4096, 256, 0, stream>>>(Qb, Ksum, Z);

  // G'[n,d] = sum_l Wob[n,l]*KVr[d,l], split-K x4 (K=256/slice); Wo folded in.
  dim3 gg(4, 4, 16);
  gemm_bt<EPI_NONE, false, false, false><<<gg, 512, LDS_DEEP, stream>>>(
      Wob, KVr, nullptr, nullptr, Pg, 1024, 1024, 256, 1024, 1024, 1024,
      0L, 1048576L, 1048576L, 0, 3, 2, nullptr, nullptr, nullptr, nullptr, nullptr);
  reduce4<<<2048, 256, 0, stream>>>(Pg, Gp);

  // final: out[t,n] = Z[t]*(sum_d Qb[t,d]*G'[n,d]) + bo[n], fp32 out
  dim3 gf(16, 4, 4);
  gemm_bt<EPI_ZBIAS_F32, false, false, false><<<gf, 512, LDS_DEEP, stream>>>(
      Qb, Gp, bo, Z, out, 4096, 1024, 1024, 1024, 1024, 1024,
      4194304L, 1048576L, 4194304L, 4096L, 3, 30, nullptr, nullptr, nullptr, nullptr, nullptr);
}